// Round 1
// baseline (136.281 us; speedup 1.0000x reference)
//
#include <hip/hip_runtime.h>
#include <math.h>

// Problem constants (from reference setup): B=4, T=512, Z=32, C=3*Z=96.
#define BB 4
#define TT 512
#define ZZ 32
#define CC 96
#define NSLICE (BB * ZZ)   // 128

// Kernel 1: per (b,z) slice:
//  - write mapped_mean[b,z,t] = mapped[b,t,z]
//  - dinv[t]  = 1 / (mapped[b,t,32+2z] + 1)
//  - L[t]     = sum_{k<t} log2(s_k / d_k), s_k = mapped[b,k,33+2z]  (clamped at -200)
__global__ __launch_bounds__(512) void prep_kernel(const float* __restrict__ mapped,
                                                   float* __restrict__ out_mean,
                                                   float* __restrict__ dinv,
                                                   float* __restrict__ Lpre) {
    const int slice = blockIdx.x;      // b*32 + z
    const int b = slice >> 5;
    const int z = slice & 31;
    const int t = threadIdx.x;

    const float* row = mapped + ((size_t)b * TT + t) * CC;
    const float meanv = row[z];
    const float dval  = row[ZZ + 2 * z] + 1.0f;
    const float sval  = (t < TT - 1) ? row[ZZ + 2 * z + 1] : 0.0f;

    out_mean[slice * TT + t] = meanv;
    const float di = 1.0f / dval;
    dinv[slice * TT + t] = di;

    // g_t = log2(s_t/d_t) <= 0 strictly (s<1<=d). s==0 -> -inf -> clamp -200,
    // which still underflows to exact 0 through exp2f in fp32.
    float g = 0.0f;
    if (t < TT - 1) g = fmaxf(log2f(sval * di), -200.0f);

    // Inclusive Hillis-Steele scan in LDS, then shift to exclusive.
    __shared__ float sh[TT];
    sh[t] = g;
    __syncthreads();
    #pragma unroll
    for (int off = 1; off < TT; off <<= 1) {
        float v = (t >= off) ? sh[t - off] : 0.0f;
        __syncthreads();
        sh[t] += v;
        __syncthreads();
    }
    const float L = (t == 0) ? 0.0f : sh[t - 1];
    Lpre[slice * TT + t] = L;
}

// Kernel 2: fill cov_tril_lower. One float4 (4 consecutive cols of one row) per thread.
// lower[i,j] = (-1)^(i-j) * exp2(L[i]-L[j]) * dinv[i]  for j<=i, else 0.
__global__ __launch_bounds__(256) void fill_kernel(const float* __restrict__ dinv,
                                                   const float* __restrict__ Lpre,
                                                   float* __restrict__ out_tril) {
    const int gid = blockIdx.x * 256 + threadIdx.x;  // float4 index
    const int slice = gid >> 16;                     // 65536 float4 per slice
    const int rem = gid & 65535;
    const int i  = rem >> 7;                         // row (128 float4 per row)
    const int j4 = (rem & 127) << 2;                 // first column of this float4

    const float* Ls = Lpre + slice * TT;
    const float Li = Ls[i];
    const float di = dinv[slice * TT + i];
    const float4 Lj = *reinterpret_cast<const float4*>(Ls + j4);

    float4 o;
    {
        const int j = j4 + 0;
        if (j > i) o.x = 0.0f;
        else { float r = exp2f(Li - Lj.x) * di; o.x = ((i - j) & 1) ? -r : r; }
    }
    {
        const int j = j4 + 1;
        if (j > i) o.y = 0.0f;
        else { float r = exp2f(Li - Lj.y) * di; o.y = ((i - j) & 1) ? -r : r; }
    }
    {
        const int j = j4 + 2;
        if (j > i) o.z = 0.0f;
        else { float r = exp2f(Li - Lj.z) * di; o.z = ((i - j) & 1) ? -r : r; }
    }
    {
        const int j = j4 + 3;
        if (j > i) o.w = 0.0f;
        else { float r = exp2f(Li - Lj.w) * di; o.w = ((i - j) & 1) ? -r : r; }
    }
    reinterpret_cast<float4*>(out_tril)[gid] = o;
}

extern "C" void kernel_launch(void* const* d_in, const int* in_sizes, int n_in,
                              void* d_out, int out_size, void* d_ws, size_t ws_size,
                              hipStream_t stream) {
    const float* mapped = (const float*)d_in[0];
    float* out = (float*)d_out;

    float* out_mean = out;                          // 4*32*512 = 65536 floats
    float* out_tril = out + NSLICE * TT;            // 4*32*512*512 floats

    float* dinv = (float*)d_ws;                     // 65536 floats (256 KB)
    float* Lpre = dinv + NSLICE * TT;               // 65536 floats (256 KB)

    prep_kernel<<<NSLICE, TT, 0, stream>>>(mapped, out_mean, dinv, Lpre);

    const int n_f4 = NSLICE * TT * TT / 4;          // 8,388,608 float4
    fill_kernel<<<n_f4 / 256, 256, 0, stream>>>(dinv, Lpre, out_tril);
}